// Round 13
// baseline (381.849 us; speedup 1.0000x reference)
//
#include <hip/hip_runtime.h>
#include <hip/hip_fp16.h>
#include <math.h>

typedef _Float16 f16;
typedef _Float16 f16x2 __attribute__((ext_vector_type(2)));
typedef _Float16 f16x8 __attribute__((ext_vector_type(8)));
typedef float f32x4 __attribute__((ext_vector_type(4)));
typedef unsigned char u8;

#define HDIM 256
#define TST 128
#define OUTD 10
#define S2LE 2.8853900817779268f   // 2*log2(e)

static __device__ __forceinline__ f16x2 pkrtz(float a, float b) {
  auto r = __builtin_amdgcn_cvt_pkrtz(a, b);
  return *(f16x2*)&r;
}

// R12 (4 waves x 64 rows, double-pump, own-chunk Gram stats, zeros-C-fold)
// + cross-phase dd prefetch (sD1 immutable -> issue reads for t+1 at end of
//   phase t; consumed after next barrier)
// + stat-Gram MFMAs hoisted to phase start (GSEL/write latency hidden)
// + setprio removed (cross-block arbitration; m190 negative for lockstep)
__global__ __launch_bounds__(256, 2) void rnn_kernel(
    const float* __restrict__ x,
    const float* __restrict__ embed_w,
    const float* __restrict__ embed_b,
    const float* __restrict__ update_w,
    const float* __restrict__ update_b,
    const float* __restrict__ gamma,
    const float* __restrict__ beta,
    const float* __restrict__ out_w,
    const float* __restrict__ out_b,
    float* __restrict__ out)
{
  __shared__ __align__(16) f16   sFR[2][8][64][8];   // 16 KB; overlays: T0 (init), sOut (epi)
  __shared__ __align__(16) float sD1[10 * 260];      // 10.4 KB; epi overlay: sOW
  __shared__ __align__(16) float sBW[HDIM];
  __shared__ __align__(16) float sRSg[HDIM];
  __shared__ __align__(16) float sST[2][16][10][2];  // [group][col][slot 2w+cp][s1,s2]
  __shared__ float sOB[16];
  __shared__ u8    sXb[TST][32];

  const int tid = threadIdx.x;
  const int w  = tid >> 6;      // 0..3
  const int l  = tid & 63;
  const int q  = l >> 4;
  const int ml = l & 15;
  const int m3 = ml & 3;
  const int base = blockIdx.x * 32;
  const int nb = w * 64 + q * 4;
  const int diagw = (q == (ml >> 2));     // lane holds Gram diag for col ml

  float* T0 = (float*)&sFR[0][0][0][0];   // [256][10] init-only overlay

  // ---------- P-init 1 ----------
  {
    float ew = embed_w[tid], eb = embed_b[tid];
    #pragma unroll
    for (int xv = 0; xv < 10; xv++)
      T0[tid * 10 + xv] = tanhf((float)xv * ew + eb);
  }
  for (int idx = tid; idx < 32 * TST; idx += 256) {
    int col = idx >> 7, tt = idx & 127;
    sXb[tt][col] = (u8)(int)x[(size_t)(base + col) * TST + tt];
  }
  if (tid < 16) {
    float v = 0.f;
    if (tid < OUTD) {
      v = out_b[tid];
      const float* orow = out_w + tid * HDIM;
      for (int k = 0; k < HDIM; k += 4) {
        float4 wv = *(const float4*)(orow + k);
        float4 bv = *(const float4*)(beta + k);
        v = fmaf(wv.x, bv.x, fmaf(wv.y, bv.y, fmaf(wv.z, bv.z, fmaf(wv.w, bv.w, v))));
      }
    }
    sOB[tid] = v;
  }
  __syncthreads();

  // ---------- P-init 2: per-n tables (n = tid) ----------
  {
    const int n = tid;
    const float* wrow = update_w + n * HDIM;
    float ty[10];
    #pragma unroll
    for (int xv = 0; xv < 10; xv++) ty[xv] = 0.f;
    float bw = 0.f, rsg = 0.f;
    for (int k = 0; k < HDIM; k += 4) {
      float4 wv4 = *(const float4*)(wrow + k);
      float4 b4  = *(const float4*)(beta + k);
      float4 g4  = *(const float4*)(gamma + k);
      bw  = fmaf(wv4.x, b4.x, fmaf(wv4.y, b4.y, fmaf(wv4.z, b4.z, fmaf(wv4.w, b4.w, bw))));
      rsg = fmaf(wv4.x, S2LE * g4.x, fmaf(wv4.y, S2LE * g4.y,
            fmaf(wv4.z, S2LE * g4.z, fmaf(wv4.w, S2LE * g4.w, rsg))));
      #pragma unroll
      for (int kk = 0; kk < 4; kk++) {
        float wv = ((const float*)&wv4)[kk];
        const float* t0r = T0 + (k + kk) * 10;
        #pragma unroll
        for (int xv = 0; xv < 10; xv++) ty[xv] = fmaf(wv, t0r[xv], ty[xv]);
      }
    }
    float ubn = update_b[n];
    sBW[n]  = S2LE * bw;
    sRSg[n] = rsg;
    #pragma unroll
    for (int xv = 0; xv < 10; xv++)
      sD1[xv * 260 + n] = S2LE * (ty[xv] + ubn + bw);
  }
  __syncthreads();

  // ---------- W_g fragments (128 regs) ----------
  f16x8 wf[4][8];
  #pragma unroll
  for (int c = 0; c < 8; c++) {
    const int k0 = c * 32 + q * 4;
    float4 g0 = *(const float4*)(gamma + k0);
    float4 g1 = *(const float4*)(gamma + k0 + 16);
    #pragma unroll
    for (int nt = 0; nt < 4; nt++) {
      const float* wrow = update_w + (w * 64 + nt * 16 + ml) * HDIM;
      float4 a0 = *(const float4*)(wrow + k0);
      float4 a1 = *(const float4*)(wrow + k0 + 16);
      f16x8 f;
      f[0]=(f16)(S2LE*g0.x*a0.x); f[1]=(f16)(S2LE*g0.y*a0.y);
      f[2]=(f16)(S2LE*g0.z*a0.z); f[3]=(f16)(S2LE*g0.w*a0.w);
      f[4]=(f16)(S2LE*g1.x*a1.x); f[5]=(f16)(S2LE*g1.y*a1.y);
      f[6]=(f16)(S2LE*g1.z*a1.z); f[7]=(f16)(S2LE*g1.w*a1.w);
      wf[nt][c] = f;
    }
  }
  f32x4 rsgr[4];
  #pragma unroll
  for (int nt = 0; nt < 4; nt++)
    rsgr[nt] = *(const f32x4*)(sRSg + nb + nt * 16);

  f16x8 ones_;
  #pragma unroll
  for (int j = 0; j < 8; j++) ones_[j] = (f16)1.f;
  const f32x4 zeros_ = {0.f, 0.f, 0.f, 0.f};

  f32x4 acc0[4], acc1[4];
  f32x4 ddA[4], ddB[4];

  // ---------- prologue t=0: tv(0) both groups -> frags (no stats) ----------
  {
    #pragma unroll
    for (int g = 0; g < 2; g++) {
      const int xv0 = (int)sXb[0][g * 16 + ml];
      const float* dp = sD1 + xv0 * 260;
      #pragma unroll
      for (int cp = 0; cp < 2; cp++) {
        union { f16x8 v8; f16x2 v2[4]; } pk;
        #pragma unroll
        for (int h = 0; h < 2; h++) {
          const int nt = 2 * cp + h;
          f32x4 dd = *(const f32x4*)(dp + nb + nt * 16);
          f32x4 bw = *(const f32x4*)(sBW + nb + nt * 16);
          float tq[4];
          #pragma unroll
          for (int r = 0; r < 4; r++) {
            float y = dd[r] - bw[r];
            float e = __builtin_amdgcn_exp2f(y);
            float tv = fmaf(-2.f, __builtin_amdgcn_rcpf(e + 1.f), 1.f);
            tq[r] = tv;
          }
          pk.v2[2 * h]     = pkrtz(tq[0], tq[1]);
          pk.v2[2 * h + 1] = pkrtz(tq[2], tq[3]);
        }
        *(f16x8*)&sFR[g][2 * w + cp][l][0] = pk.v8;
      }
    }
    __syncthreads();
  }

#define MMG(FB, CC, CUR, NXT, ACC)                                             \
    { if ((CC) < 7) NXT = *(const f16x8*)((FB) + ((CC) + 1) * 512 + l * 8);    \
      ACC[0] = __builtin_amdgcn_mfma_f32_16x16x32_f16(wf[0][CC], CUR, ACC[0],0,0,0); \
      ACC[1] = __builtin_amdgcn_mfma_f32_16x16x32_f16(wf[1][CC], CUR, ACC[1],0,0,0); \
      ACC[2] = __builtin_amdgcn_mfma_f32_16x16x32_f16(wf[2][CC], CUR, ACC[2],0,0,0); \
      ACC[3] = __builtin_amdgcn_mfma_f32_16x16x32_f16(wf[3][CC], CUR, ACC[3],0,0,0); }

#define GSEL(AG, SEL)                                                          \
    { SEL = AG[0];                                                             \
      SEL = (m3 == 1) ? AG[1] : SEL;                                           \
      SEL = (m3 == 2) ? AG[2] : SEL;                                           \
      SEL = (m3 == 3) ? AG[3] : SEL; }

#define STATRD(G, S1, S2)                                                      \
    { const float* sp_ = &sST[G][ml][0][0];                                    \
      f32x4 a0_ = *(const f32x4*)(sp_);                                        \
      f32x4 a1_ = *(const f32x4*)(sp_ + 4);                                    \
      f32x4 a2_ = *(const f32x4*)(sp_ + 8);                                    \
      f32x4 a3_ = *(const f32x4*)(sp_ + 12);                                   \
      S1 = ((a0_[0] + a0_[2]) + (a1_[0] + a1_[2]))                             \
         + ((a2_[0] + a2_[2]) + (a3_[0] + a3_[2]));                            \
      S2 = ((a0_[1] + a0_[3]) + (a1_[1] + a1_[3]))                             \
         + ((a2_[1] + a2_[3]) + (a3_[1] + a3_[3])); }

// own-chunk stats (epilogue / prologue use): loads + MFMAs + write
#define STATOWN(FB, G)                                                         \
    { f16x8 ro0_ = *(const f16x8*)((FB) + (2 * w) * 512 + l * 8);              \
      f16x8 ro1_ = *(const f16x8*)((FB) + (2 * w + 1) * 512 + l * 8);          \
      f32x4 aG0_ = __builtin_amdgcn_mfma_f32_16x16x32_f16(ro0_, ro0_, zeros_,0,0,0); \
      f32x4 aS0_ = __builtin_amdgcn_mfma_f32_16x16x32_f16(ones_, ro0_, zeros_,0,0,0); \
      f32x4 aG1_ = __builtin_amdgcn_mfma_f32_16x16x32_f16(ro1_, ro1_, zeros_,0,0,0); \
      f32x4 aS1_ = __builtin_amdgcn_mfma_f32_16x16x32_f16(ones_, ro1_, zeros_,0,0,0); \
      float sel0_, sel1_;                                                      \
      GSEL(aG0_, sel0_)                                                        \
      GSEL(aG1_, sel1_)                                                        \
      if (diagw)                                                               \
        *(f32x4*)&sST[G][ml][2 * w][0] =                                       \
            (f32x4){aS0_[0], sel0_, aS1_[0], sel1_};                           \
    }

#define SLICE(S, ACCE, DD)                                                     \
    { _Pragma("unroll") for (int r_ = 0; r_ < 4; r_++) {                       \
        float y_ = fmaf(rs_, ACCE[S][r_], fmaf(-rm_, rsgr[S][r_], DD[S][r_])); \
        float e_ = __builtin_amdgcn_exp2f(y_);                                 \
        tv_[S][r_] = fmaf(-2.f, __builtin_amdgcn_rcpf(e_ + 1.f), 1.f); } }

#define PACK(GE, CP)                                                           \
    { union { f16x8 v8; f16x2 v2[4]; } k_;                                     \
      k_.v2[0] = pkrtz(tv_[2*(CP)][0],   tv_[2*(CP)][1]);                      \
      k_.v2[1] = pkrtz(tv_[2*(CP)][2],   tv_[2*(CP)][3]);                      \
      k_.v2[2] = pkrtz(tv_[2*(CP)+1][0], tv_[2*(CP)+1][1]);                    \
      k_.v2[3] = pkrtz(tv_[2*(CP)+1][2], tv_[2*(CP)+1][3]);                    \
      *(f16x8*)&sFR[GE][2 * w + (CP)][l][0] = k_.v8; }

// PHASE: stat-Gram MFMAs first (latency hidden under main cluster); main
// MFMA group GM -> ACCM interleaved with elementwise of group GE (step TE,
// consuming prefetched DD); dd(TN) prefetched into DD at phase end.
#define PHASE(TE, TN, GM, GE, XOFF, ACCM, ACCE, DD)                            \
  {                                                                            \
    const f16* fbm_ = &sFR[GM][0][0][0];                                       \
    f16x8 ro0_ = *(const f16x8*)(fbm_ + (2 * w) * 512 + l * 8);                \
    f16x8 ro1_ = *(const f16x8*)(fbm_ + (2 * w + 1) * 512 + l * 8);            \
    f32x4 aG0_ = __builtin_amdgcn_mfma_f32_16x16x32_f16(ro0_, ro0_, zeros_,0,0,0); \
    f32x4 aS0_ = __builtin_amdgcn_mfma_f32_16x16x32_f16(ones_, ro0_, zeros_,0,0,0); \
    f32x4 aG1_ = __builtin_amdgcn_mfma_f32_16x16x32_f16(ro1_, ro1_, zeros_,0,0,0); \
    f32x4 aS1_ = __builtin_amdgcn_mfma_f32_16x16x32_f16(ones_, ro1_, zeros_,0,0,0); \
    float s1_, s2_;                                                            \
    STATRD(GE, s1_, s2_)                                                       \
    f16x8 rA_ = *(const f16x8*)(fbm_ + l * 8);                                 \
    f16x8 rB_;                                                                 \
    f32x4 tv_[4];                                                              \
    rB_ = *(const f16x8*)(fbm_ + 512 + l * 8);                                 \
    ACCM[0] = __builtin_amdgcn_mfma_f32_16x16x32_f16(wf[0][0], rA_, zeros_,0,0,0); \
    ACCM[1] = __builtin_amdgcn_mfma_f32_16x16x32_f16(wf[1][0], rA_, zeros_,0,0,0); \
    ACCM[2] = __builtin_amdgcn_mfma_f32_16x16x32_f16(wf[2][0], rA_, zeros_,0,0,0); \
    ACCM[3] = __builtin_amdgcn_mfma_f32_16x16x32_f16(wf[3][0], rA_, zeros_,0,0,0); \
    MMG(fbm_, 1, rB_, rA_, ACCM)                                               \
    float mu_ = s1_ * (1.f / 256.f);                                           \
    float rs_ = __frsqrt_rn(fmaf(s2_, 1.f / 256.f, -mu_ * mu_) + 1e-5f);       \
    float rm_ = rs_ * mu_;                                                     \
    SLICE(0, ACCE, DD)                                                         \
    MMG(fbm_, 2, rA_, rB_, ACCM)                                               \
    MMG(fbm_, 3, rB_, rA_, ACCM)                                               \
    SLICE(1, ACCE, DD)                                                         \
    PACK(GE, 0)                                                                \
    MMG(fbm_, 4, rA_, rB_, ACCM)                                               \
    MMG(fbm_, 5, rB_, rA_, ACCM)                                               \
    SLICE(2, ACCE, DD)                                                         \
    MMG(fbm_, 6, rA_, rB_, ACCM)                                               \
    MMG(fbm_, 7, rB_, rA_, ACCM)                                               \
    SLICE(3, ACCE, DD)                                                         \
    PACK(GE, 1)                                                                \
    {                                                                          \
      const int xvn_ = (int)sXb[TN][XOFF + ml];                                \
      const float* dpn_ = sD1 + xvn_ * 260 + nb;                               \
      _Pragma("unroll") for (int n_ = 0; n_ < 4; n_++)                         \
        DD[n_] = *(const f32x4*)(dpn_ + n_ * 16);                              \
    }                                                                          \
    {                                                                          \
      float sel0_, sel1_;                                                      \
      GSEL(aG0_, sel0_)                                                        \
      GSEL(aG1_, sel1_)                                                        \
      if (diagw)                                                               \
        *(f32x4*)&sST[GM][ml][2 * w][0] =                                      \
            (f32x4){aS0_[0], sel0_, aS1_[0], sel1_};                           \
    }                                                                          \
    __syncthreads();                                                           \
  }

  // ---------- P0(1): MFMA g0 + own-chunk stats(g0,0) + dd(1) preload ----------
  {
    const f16* fbm_ = &sFR[0][0][0][0];
    f16x8 rA_ = *(const f16x8*)(fbm_ + l * 8);
    f16x8 rB_;
    rB_ = *(const f16x8*)(fbm_ + 512 + l * 8);
    acc0[0] = __builtin_amdgcn_mfma_f32_16x16x32_f16(wf[0][0], rA_, zeros_,0,0,0);
    acc0[1] = __builtin_amdgcn_mfma_f32_16x16x32_f16(wf[1][0], rA_, zeros_,0,0,0);
    acc0[2] = __builtin_amdgcn_mfma_f32_16x16x32_f16(wf[2][0], rA_, zeros_,0,0,0);
    acc0[3] = __builtin_amdgcn_mfma_f32_16x16x32_f16(wf[3][0], rA_, zeros_,0,0,0);
    MMG(fbm_, 1, rB_, rA_, acc0)
    MMG(fbm_, 2, rA_, rB_, acc0)
    MMG(fbm_, 3, rB_, rA_, acc0)
    MMG(fbm_, 4, rA_, rB_, acc0)
    MMG(fbm_, 5, rB_, rA_, acc0)
    MMG(fbm_, 6, rA_, rB_, acc0)
    MMG(fbm_, 7, rB_, rA_, acc0)
    STATOWN(fbm_, 0)
    // preload dd(1) for both groups
    {
      const int xva = (int)sXb[1][ml];
      const float* dpa = sD1 + xva * 260 + nb;
      const int xvb = (int)sXb[1][16 + ml];
      const float* dpb = sD1 + xvb * 260 + nb;
      #pragma unroll
      for (int n_ = 0; n_ < 4; n_++) {
        ddA[n_] = *(const f32x4*)(dpa + n_ * 16);
        ddB[n_] = *(const f32x4*)(dpb + n_ * 16);
      }
    }
    __syncthreads();
  }

  // ---------- main loop ----------
  #pragma unroll 1
  for (int t = 1; t <= 126; t++) {
    PHASE(t, t + 1, 1, 0, 0,  acc1, acc0, ddA)
    PHASE(t, t + 1, 0, 1, 16, acc0, acc1, ddB)
  }
  PHASE(127, 127, 1, 0, 0,  acc1, acc0, ddA)
  PHASE(127, 127, 0, 1, 16, acc0, acc1, ddB)
  // post: sFR[0]=tv(g0,127), sFR[1]=tv(g1,127);
  //       sST[0]=stats(g0,127); sST[1]=stats(g1,126) stale -> recompute.

  // ---------- epilogue ----------
  {
    const f16* fb1 = &sFR[1][0][0][0];
    STATOWN(fb1, 1)
    f16x8 fin0[2], fin1[2];
    #pragma unroll
    for (int cp = 0; cp < 2; cp++) {
      fin0[cp] = *(const f16x8*)&sFR[0][2 * w + cp][l][0];
      fin1[cp] = *(const f16x8*)&sFR[1][2 * w + cp][l][0];
    }
    __syncthreads();

    float rsF[2], nmF[2];
    {
      float s1, s2;
      STATRD(0, s1, s2)
      float mu = s1 * (1.f / 256.f);
      float ve = fmaf(s2, 1.f / 256.f, -mu * mu) + 1e-5f;
      rsF[0] = __frsqrt_rn(ve); nmF[0] = -rsF[0] * mu;
      STATRD(1, s1, s2)
      mu = s1 * (1.f / 256.f);
      ve = fmaf(s2, 1.f / 256.f, -mu * mu) + 1e-5f;
      rsF[1] = __frsqrt_rn(ve); nmF[1] = -rsF[1] * mu;
    }

    f16* sOW = (f16*)sD1;
    for (int idx = tid; idx < 512; idx += 256) {
      int c = idx >> 6, l2 = idx & 63, q2 = l2 >> 4, o = l2 & 15;
      int k0 = c * 32 + q2 * 4;
      f16x8 f;
      #pragma unroll
      for (int j = 0; j < 8; j++) f[j] = (f16)0.f;
      if (o < OUTD) {
        const float* orow = out_w + o * HDIM;
        float4 a0 = *(const float4*)(orow + k0);
        float4 a1 = *(const float4*)(orow + k0 + 16);
        float4 g0 = *(const float4*)(gamma + k0);
        float4 g1 = *(const float4*)(gamma + k0 + 16);
        f[0]=(f16)(g0.x*a0.x); f[1]=(f16)(g0.y*a0.y); f[2]=(f16)(g0.z*a0.z); f[3]=(f16)(g0.w*a0.w);
        f[4]=(f16)(g1.x*a1.x); f[5]=(f16)(g1.y*a1.y); f[6]=(f16)(g1.z*a1.z); f[7]=(f16)(g1.w*a1.w);
      }
      *(f16x8*)(sOW + idx * 8) = f;
    }
    __syncthreads();

    float* sOut = (float*)&sFR[0][0][0][0];  // [2][4][16][16] f32 = 8 KB overlay
    #pragma unroll
    for (int g = 0; g < 2; g++) {
      f32x4 aO = zeros_;
      #pragma unroll
      for (int cp = 0; cp < 2; cp++) {
        f16x8 fr = (g == 0) ? fin0[cp] : fin1[cp];
        f16x8 af;
        #pragma unroll
        for (int j = 0; j < 8; j++)
          af[j] = (f16)fmaf(rsF[g], (float)fr[j], nmF[g]);
        f16x8 of = *(const f16x8*)(sOW + ((size_t)(2 * w + cp) * 64 + l) * 8);
        aO = __builtin_amdgcn_mfma_f32_16x16x32_f16(of, af, aO, 0, 0, 0);
      }
      #pragma unroll
      for (int r = 0; r < 4; r++)
        sOut[((g * 4 + w) * 16 + ml) * 16 + q * 4 + r] = aO[r];
    }
    __syncthreads();
    for (int idx = tid; idx < 32 * OUTD; idx += 256) {
      int m = idx / OUTD, o = idx - m * OUTD;
      int g = m >> 4, mm = m & 15;
      float s = 0.f;
      #pragma unroll
      for (int ww = 0; ww < 4; ww++) s += sOut[((g * 4 + ww) * 16 + mm) * 16 + o];
      out[(size_t)(base + m) * OUTD + o] = s + sOB[o];
    }
  }
}

extern "C" void kernel_launch(void* const* d_in, const int* in_sizes, int n_in,
                              void* d_out, int out_size, void* d_ws, size_t ws_size,
                              hipStream_t stream) {
  const float* x   = (const float*)d_in[0];
  const float* ew  = (const float*)d_in[1];
  const float* eb  = (const float*)d_in[2];
  const float* uw  = (const float*)d_in[3];
  const float* ub  = (const float*)d_in[4];
  const float* g   = (const float*)d_in[5];
  const float* be  = (const float*)d_in[6];
  const float* ow  = (const float*)d_in[7];
  const float* ob  = (const float*)d_in[8];
  float* out = (float*)d_out;

  const int B = in_sizes[0] / TST;      // 16384
  const int grid = B / 32;              // 512 blocks = 2/CU, one round
  hipLaunchKernelGGL(rnn_kernel, dim3(grid), dim3(256), 0, stream,
                     x, ew, eb, uw, ub, g, be, ow, ob, out);
}

// Round 14
// 336.469 us; speedup vs baseline: 1.1349x; 1.1349x over previous
//
#include <hip/hip_runtime.h>
#include <hip/hip_fp16.h>
#include <math.h>

typedef _Float16 f16;
typedef _Float16 f16x2 __attribute__((ext_vector_type(2)));
typedef _Float16 f16x8 __attribute__((ext_vector_type(8)));
typedef float f32x4 __attribute__((ext_vector_type(4)));
typedef unsigned char u8;

#define HDIM 256
#define TST 128
#define OUTD 10
#define S2LE 2.8853900817779268f   // 2*log2(e)

static __device__ __forceinline__ f16x2 pkrtz(float a, float b) {
  auto r = __builtin_amdgcn_cvt_pkrtz(a, b);
  return *(f16x2*)&r;
}

// R12 exactly (4 waves x 64 rows, double-pump, own-chunk Gram stats,
// zeros-C-fold; 318 us verified), minus s_setprio (T5 null-to-negative on
// barrier-synced structures, m190; zero register cost).
__global__ __launch_bounds__(256, 2) void rnn_kernel(
    const float* __restrict__ x,
    const float* __restrict__ embed_w,
    const float* __restrict__ embed_b,
    const float* __restrict__ update_w,
    const float* __restrict__ update_b,
    const float* __restrict__ gamma,
    const float* __restrict__ beta,
    const float* __restrict__ out_w,
    const float* __restrict__ out_b,
    float* __restrict__ out)
{
  __shared__ __align__(16) f16   sFR[2][8][64][8];   // 16 KB; overlays: T0 (init), sOut (epi)
  __shared__ __align__(16) float sD1[10 * 260];      // 10.4 KB; epi overlay: sOW
  __shared__ __align__(16) float sBW[HDIM];
  __shared__ __align__(16) float sRSg[HDIM];
  __shared__ __align__(16) float sST[2][16][10][2];  // [group][col][slot 2w+cp][s1,s2]
  __shared__ float sOB[16];
  __shared__ u8    sXb[TST][32];

  const int tid = threadIdx.x;
  const int w  = tid >> 6;      // 0..3
  const int l  = tid & 63;
  const int q  = l >> 4;
  const int ml = l & 15;
  const int m3 = ml & 3;
  const int base = blockIdx.x * 32;
  const int nb = w * 64 + q * 4;
  const int diagw = (q == (ml >> 2));     // lane holds Gram diag for col ml

  float* T0 = (float*)&sFR[0][0][0][0];   // [256][10] init-only overlay

  // ---------- P-init 1 ----------
  {
    float ew = embed_w[tid], eb = embed_b[tid];
    #pragma unroll
    for (int xv = 0; xv < 10; xv++)
      T0[tid * 10 + xv] = tanhf((float)xv * ew + eb);
  }
  for (int idx = tid; idx < 32 * TST; idx += 256) {
    int col = idx >> 7, tt = idx & 127;
    sXb[tt][col] = (u8)(int)x[(size_t)(base + col) * TST + tt];
  }
  if (tid < 16) {
    float v = 0.f;
    if (tid < OUTD) {
      v = out_b[tid];
      const float* orow = out_w + tid * HDIM;
      for (int k = 0; k < HDIM; k += 4) {
        float4 wv = *(const float4*)(orow + k);
        float4 bv = *(const float4*)(beta + k);
        v = fmaf(wv.x, bv.x, fmaf(wv.y, bv.y, fmaf(wv.z, bv.z, fmaf(wv.w, bv.w, v))));
      }
    }
    sOB[tid] = v;
  }
  __syncthreads();

  // ---------- P-init 2: per-n tables (n = tid) ----------
  {
    const int n = tid;
    const float* wrow = update_w + n * HDIM;
    float ty[10];
    #pragma unroll
    for (int xv = 0; xv < 10; xv++) ty[xv] = 0.f;
    float bw = 0.f, rsg = 0.f;
    for (int k = 0; k < HDIM; k += 4) {
      float4 wv4 = *(const float4*)(wrow + k);
      float4 b4  = *(const float4*)(beta + k);
      float4 g4  = *(const float4*)(gamma + k);
      bw  = fmaf(wv4.x, b4.x, fmaf(wv4.y, b4.y, fmaf(wv4.z, b4.z, fmaf(wv4.w, b4.w, bw))));
      rsg = fmaf(wv4.x, S2LE * g4.x, fmaf(wv4.y, S2LE * g4.y,
            fmaf(wv4.z, S2LE * g4.z, fmaf(wv4.w, S2LE * g4.w, rsg))));
      #pragma unroll
      for (int kk = 0; kk < 4; kk++) {
        float wv = ((const float*)&wv4)[kk];
        const float* t0r = T0 + (k + kk) * 10;
        #pragma unroll
        for (int xv = 0; xv < 10; xv++) ty[xv] = fmaf(wv, t0r[xv], ty[xv]);
      }
    }
    float ubn = update_b[n];
    sBW[n]  = S2LE * bw;
    sRSg[n] = rsg;
    #pragma unroll
    for (int xv = 0; xv < 10; xv++)
      sD1[xv * 260 + n] = S2LE * (ty[xv] + ubn + bw);
  }
  __syncthreads();

  // ---------- W_g fragments (128 regs) ----------
  f16x8 wf[4][8];
  #pragma unroll
  for (int c = 0; c < 8; c++) {
    const int k0 = c * 32 + q * 4;
    float4 g0 = *(const float4*)(gamma + k0);
    float4 g1 = *(const float4*)(gamma + k0 + 16);
    #pragma unroll
    for (int nt = 0; nt < 4; nt++) {
      const float* wrow = update_w + (w * 64 + nt * 16 + ml) * HDIM;
      float4 a0 = *(const float4*)(wrow + k0);
      float4 a1 = *(const float4*)(wrow + k0 + 16);
      f16x8 f;
      f[0]=(f16)(S2LE*g0.x*a0.x); f[1]=(f16)(S2LE*g0.y*a0.y);
      f[2]=(f16)(S2LE*g0.z*a0.z); f[3]=(f16)(S2LE*g0.w*a0.w);
      f[4]=(f16)(S2LE*g1.x*a1.x); f[5]=(f16)(S2LE*g1.y*a1.y);
      f[6]=(f16)(S2LE*g1.z*a1.z); f[7]=(f16)(S2LE*g1.w*a1.w);
      wf[nt][c] = f;
    }
  }
  f32x4 rsgr[4];
  #pragma unroll
  for (int nt = 0; nt < 4; nt++)
    rsgr[nt] = *(const f32x4*)(sRSg + nb + nt * 16);

  f16x8 ones_;
  #pragma unroll
  for (int j = 0; j < 8; j++) ones_[j] = (f16)1.f;
  const f32x4 zeros_ = {0.f, 0.f, 0.f, 0.f};

  f32x4 acc0[4], acc1[4];

  // ---------- prologue t=0: tv(0) both groups -> frags (no stats) ----------
  {
    #pragma unroll
    for (int g = 0; g < 2; g++) {
      const int xv0 = (int)sXb[0][g * 16 + ml];
      const float* dp = sD1 + xv0 * 260;
      #pragma unroll
      for (int cp = 0; cp < 2; cp++) {
        union { f16x8 v8; f16x2 v2[4]; } pk;
        #pragma unroll
        for (int h = 0; h < 2; h++) {
          const int nt = 2 * cp + h;
          f32x4 dd = *(const f32x4*)(dp + nb + nt * 16);
          f32x4 bw = *(const f32x4*)(sBW + nb + nt * 16);
          float tq[4];
          #pragma unroll
          for (int r = 0; r < 4; r++) {
            float y = dd[r] - bw[r];
            float e = __builtin_amdgcn_exp2f(y);
            float tv = fmaf(-2.f, __builtin_amdgcn_rcpf(e + 1.f), 1.f);
            tq[r] = tv;
          }
          pk.v2[2 * h]     = pkrtz(tq[0], tq[1]);
          pk.v2[2 * h + 1] = pkrtz(tq[2], tq[3]);
        }
        *(f16x8*)&sFR[g][2 * w + cp][l][0] = pk.v8;
      }
    }
    __syncthreads();
  }

#define MMG(FB, CC, CUR, NXT, ACC)                                             \
    { if ((CC) < 7) NXT = *(const f16x8*)((FB) + ((CC) + 1) * 512 + l * 8);    \
      ACC[0] = __builtin_amdgcn_mfma_f32_16x16x32_f16(wf[0][CC], CUR, ACC[0],0,0,0); \
      ACC[1] = __builtin_amdgcn_mfma_f32_16x16x32_f16(wf[1][CC], CUR, ACC[1],0,0,0); \
      ACC[2] = __builtin_amdgcn_mfma_f32_16x16x32_f16(wf[2][CC], CUR, ACC[2],0,0,0); \
      ACC[3] = __builtin_amdgcn_mfma_f32_16x16x32_f16(wf[3][CC], CUR, ACC[3],0,0,0); }

#define GSEL(AG, SEL)                                                          \
    { SEL = AG[0];                                                             \
      SEL = (m3 == 1) ? AG[1] : SEL;                                           \
      SEL = (m3 == 2) ? AG[2] : SEL;                                           \
      SEL = (m3 == 3) ? AG[3] : SEL; }

#define STATRD(G, S1, S2)                                                      \
    { const float* sp_ = &sST[G][ml][0][0];                                    \
      f32x4 a0_ = *(const f32x4*)(sp_);                                        \
      f32x4 a1_ = *(const f32x4*)(sp_ + 4);                                    \
      f32x4 a2_ = *(const f32x4*)(sp_ + 8);                                    \
      f32x4 a3_ = *(const f32x4*)(sp_ + 12);                                   \
      S1 = ((a0_[0] + a0_[2]) + (a1_[0] + a1_[2]))                             \
         + ((a2_[0] + a2_[2]) + (a3_[0] + a3_[2]));                            \
      S2 = ((a0_[1] + a0_[3]) + (a1_[1] + a1_[3]))                             \
         + ((a2_[1] + a2_[3]) + (a3_[1] + a3_[3])); }

// own-chunk stats for frags of group buffer FB (chunks 2w, 2w+1) -> sST[G]
#define STATOWN(FB, G)                                                         \
    { f16x8 ro0_ = *(const f16x8*)((FB) + (2 * w) * 512 + l * 8);              \
      f16x8 ro1_ = *(const f16x8*)((FB) + (2 * w + 1) * 512 + l * 8);          \
      f32x4 aG0_ = __builtin_amdgcn_mfma_f32_16x16x32_f16(ro0_, ro0_, zeros_,0,0,0); \
      f32x4 aS0_ = __builtin_amdgcn_mfma_f32_16x16x32_f16(ones_, ro0_, zeros_,0,0,0); \
      f32x4 aG1_ = __builtin_amdgcn_mfma_f32_16x16x32_f16(ro1_, ro1_, zeros_,0,0,0); \
      f32x4 aS1_ = __builtin_amdgcn_mfma_f32_16x16x32_f16(ones_, ro1_, zeros_,0,0,0); \
      float sel0_, sel1_;                                                      \
      GSEL(aG0_, sel0_)                                                        \
      GSEL(aG1_, sel1_)                                                        \
      if (diagw)                                                               \
        *(f32x4*)&sST[G][ml][2 * w][0] =                                       \
            (f32x4){aS0_[0], sel0_, aS1_[0], sel1_};                           \
    }

#define SLICE(S, ACCE)                                                         \
    { _Pragma("unroll") for (int r_ = 0; r_ < 4; r_++) {                       \
        float y_ = fmaf(rs_, ACCE[S][r_], fmaf(-rm_, rsgr[S][r_], dd_[S][r_]));\
        float e_ = __builtin_amdgcn_exp2f(y_);                                 \
        tv_[S][r_] = fmaf(-2.f, __builtin_amdgcn_rcpf(e_ + 1.f), 1.f); } }

#define PACK(GE, CP)                                                           \
    { union { f16x8 v8; f16x2 v2[4]; } k_;                                     \
      k_.v2[0] = pkrtz(tv_[2*(CP)][0],   tv_[2*(CP)][1]);                      \
      k_.v2[1] = pkrtz(tv_[2*(CP)][2],   tv_[2*(CP)][3]);                      \
      k_.v2[2] = pkrtz(tv_[2*(CP)+1][0], tv_[2*(CP)+1][1]);                    \
      k_.v2[3] = pkrtz(tv_[2*(CP)+1][2], tv_[2*(CP)+1][3]);                    \
      *(f16x8*)&sFR[GE][2 * w + (CP)][l][0] = k_.v8; }

// PHASE: MFMA group GM (frags sFR[GM] -> ACCM; own-chunk Gram -> sST[GM]) ||
// elementwise group GE at step TE (consumes ACCE + sST[GE]; packs tv -> sFR[GE]).
#define PHASE(TE, GM, GE, XOFF, ACCM, ACCE)                                    \
  {                                                                            \
    float s1_, s2_;                                                            \
    STATRD(GE, s1_, s2_)                                                       \
    const int xv_ = (int)sXb[TE][XOFF + ml];                                   \
    const float* dp_ = sD1 + xv_ * 260 + nb;                                   \
    f32x4 dd_[4];                                                              \
    _Pragma("unroll") for (int n_ = 0; n_ < 4; n_++)                           \
      dd_[n_] = *(const f32x4*)(dp_ + n_ * 16);                                \
    const f16* fbm_ = &sFR[GM][0][0][0];                                       \
    f16x8 rA_ = *(const f16x8*)(fbm_ + l * 8);                                 \
    f16x8 rB_;                                                                 \
    f32x4 tv_[4];                                                              \
    rB_ = *(const f16x8*)(fbm_ + 512 + l * 8);                                 \
    ACCM[0] = __builtin_amdgcn_mfma_f32_16x16x32_f16(wf[0][0], rA_, zeros_,0,0,0); \
    ACCM[1] = __builtin_amdgcn_mfma_f32_16x16x32_f16(wf[1][0], rA_, zeros_,0,0,0); \
    ACCM[2] = __builtin_amdgcn_mfma_f32_16x16x32_f16(wf[2][0], rA_, zeros_,0,0,0); \
    ACCM[3] = __builtin_amdgcn_mfma_f32_16x16x32_f16(wf[3][0], rA_, zeros_,0,0,0); \
    MMG(fbm_, 1, rB_, rA_, ACCM)                                               \
    float mu_ = s1_ * (1.f / 256.f);                                           \
    float rs_ = __frsqrt_rn(fmaf(s2_, 1.f / 256.f, -mu_ * mu_) + 1e-5f);       \
    float rm_ = rs_ * mu_;                                                     \
    SLICE(0, ACCE)                                                             \
    MMG(fbm_, 2, rA_, rB_, ACCM)                                               \
    MMG(fbm_, 3, rB_, rA_, ACCM)                                               \
    SLICE(1, ACCE)                                                             \
    PACK(GE, 0)                                                                \
    MMG(fbm_, 4, rA_, rB_, ACCM)                                               \
    MMG(fbm_, 5, rB_, rA_, ACCM)                                               \
    SLICE(2, ACCE)                                                             \
    MMG(fbm_, 6, rA_, rB_, ACCM)                                               \
    MMG(fbm_, 7, rB_, rA_, ACCM)                                               \
    SLICE(3, ACCE)                                                             \
    PACK(GE, 1)                                                                \
    STATOWN(fbm_, GM)                                                          \
    __syncthreads();                                                           \
  }

  // ---------- P0(1): MFMA g0 + own-chunk stats(g0,0) ----------
  {
    const f16* fbm_ = &sFR[0][0][0][0];
    f16x8 rA_ = *(const f16x8*)(fbm_ + l * 8);
    f16x8 rB_;
    rB_ = *(const f16x8*)(fbm_ + 512 + l * 8);
    acc0[0] = __builtin_amdgcn_mfma_f32_16x16x32_f16(wf[0][0], rA_, zeros_,0,0,0);
    acc0[1] = __builtin_amdgcn_mfma_f32_16x16x32_f16(wf[1][0], rA_, zeros_,0,0,0);
    acc0[2] = __builtin_amdgcn_mfma_f32_16x16x32_f16(wf[2][0], rA_, zeros_,0,0,0);
    acc0[3] = __builtin_amdgcn_mfma_f32_16x16x32_f16(wf[3][0], rA_, zeros_,0,0,0);
    MMG(fbm_, 1, rB_, rA_, acc0)
    MMG(fbm_, 2, rA_, rB_, acc0)
    MMG(fbm_, 3, rB_, rA_, acc0)
    MMG(fbm_, 4, rA_, rB_, acc0)
    MMG(fbm_, 5, rB_, rA_, acc0)
    MMG(fbm_, 6, rA_, rB_, acc0)
    MMG(fbm_, 7, rB_, rA_, acc0)
    STATOWN(fbm_, 0)
    __syncthreads();
  }

  // ---------- main loop: 2 phases per step, single-buffered sST ----------
  #pragma unroll 1
  for (int t = 1; t <= 127; t++) {
    PHASE(t, 1, 0, 0,  acc1, acc0)
    PHASE(t, 0, 1, 16, acc0, acc1)
  }
  // post: sFR[0]=tv(g0,127), sFR[1]=tv(g1,127);
  //       sST[0]=stats(g0,127); sST[1]=stats(g1,126) stale -> recompute.

  // ---------- epilogue ----------
  {
    const f16* fb1 = &sFR[1][0][0][0];
    STATOWN(fb1, 1)
    f16x8 fin0[2], fin1[2];
    #pragma unroll
    for (int cp = 0; cp < 2; cp++) {
      fin0[cp] = *(const f16x8*)&sFR[0][2 * w + cp][l][0];
      fin1[cp] = *(const f16x8*)&sFR[1][2 * w + cp][l][0];
    }
    __syncthreads();

    float rsF[2], nmF[2];
    {
      float s1, s2;
      STATRD(0, s1, s2)
      float mu = s1 * (1.f / 256.f);
      float ve = fmaf(s2, 1.f / 256.f, -mu * mu) + 1e-5f;
      rsF[0] = __frsqrt_rn(ve); nmF[0] = -rsF[0] * mu;
      STATRD(1, s1, s2)
      mu = s1 * (1.f / 256.f);
      ve = fmaf(s2, 1.f / 256.f, -mu * mu) + 1e-5f;
      rsF[1] = __frsqrt_rn(ve); nmF[1] = -rsF[1] * mu;
    }

    f16* sOW = (f16*)sD1;
    for (int idx = tid; idx < 512; idx += 256) {
      int c = idx >> 6, l2 = idx & 63, q2 = l2 >> 4, o = l2 & 15;
      int k0 = c * 32 + q2 * 4;
      f16x8 f;
      #pragma unroll
      for (int j = 0; j < 8; j++) f[j] = (f16)0.f;
      if (o < OUTD) {
        const float* orow = out_w + o * HDIM;
        float4 a0 = *(const float4*)(orow + k0);
        float4 a1 = *(const float4*)(orow + k0 + 16);
        float4 g0 = *(const float4*)(gamma + k0);
        float4 g1 = *(const float4*)(gamma + k0 + 16);
        f[0]=(f16)(g0.x*a0.x); f[1]=(f16)(g0.y*a0.y); f[2]=(f16)(g0.z*a0.z); f[3]=(f16)(g0.w*a0.w);
        f[4]=(f16)(g1.x*a1.x); f[5]=(f16)(g1.y*a1.y); f[6]=(f16)(g1.z*a1.z); f[7]=(f16)(g1.w*a1.w);
      }
      *(f16x8*)(sOW + idx * 8) = f;
    }
    __syncthreads();

    float* sOut = (float*)&sFR[0][0][0][0];  // [2][4][16][16] f32 = 8 KB overlay
    #pragma unroll
    for (int g = 0; g < 2; g++) {
      f32x4 aO = zeros_;
      #pragma unroll
      for (int cp = 0; cp < 2; cp++) {
        f16x8 fr = (g == 0) ? fin0[cp] : fin1[cp];
        f16x8 af;
        #pragma unroll
        for (int j = 0; j < 8; j++)
          af[j] = (f16)fmaf(rsF[g], (float)fr[j], nmF[g]);
        f16x8 of = *(const f16x8*)(sOW + ((size_t)(2 * w + cp) * 64 + l) * 8);
        aO = __builtin_amdgcn_mfma_f32_16x16x32_f16(of, af, aO, 0, 0, 0);
      }
      #pragma unroll
      for (int r = 0; r < 4; r++)
        sOut[((g * 4 + w) * 16 + ml) * 16 + q * 4 + r] = aO[r];
    }
    __syncthreads();
    for (int idx = tid; idx < 32 * OUTD; idx += 256) {
      int m = idx / OUTD, o = idx - m * OUTD;
      int g = m >> 4, mm = m & 15;
      float s = 0.f;
      #pragma unroll
      for (int ww = 0; ww < 4; ww++) s += sOut[((g * 4 + ww) * 16 + mm) * 16 + o];
      out[(size_t)(base + m) * OUTD + o] = s + sOB[o];
    }
  }
}

extern "C" void kernel_launch(void* const* d_in, const int* in_sizes, int n_in,
                              void* d_out, int out_size, void* d_ws, size_t ws_size,
                              hipStream_t stream) {
  const float* x   = (const float*)d_in[0];
  const float* ew  = (const float*)d_in[1];
  const float* eb  = (const float*)d_in[2];
  const float* uw  = (const float*)d_in[3];
  const float* ub  = (const float*)d_in[4];
  const float* g   = (const float*)d_in[5];
  const float* be  = (const float*)d_in[6];
  const float* ow  = (const float*)d_in[7];
  const float* ob  = (const float*)d_in[8];
  float* out = (float*)d_out;

  const int B = in_sizes[0] / TST;      // 16384
  const int grid = B / 32;              // 512 blocks = 2/CU, one round
  hipLaunchKernelGGL(rnn_kernel, dim3(grid), dim3(256), 0, stream,
                     x, ew, eb, uw, ub, g, be, ow, ob, out);
}

// Round 15
// 336.397 us; speedup vs baseline: 1.1351x; 1.0002x over previous
//
#include <hip/hip_runtime.h>
#include <hip/hip_fp16.h>
#include <math.h>

typedef _Float16 f16;
typedef _Float16 f16x2 __attribute__((ext_vector_type(2)));
typedef _Float16 f16x8 __attribute__((ext_vector_type(8)));
typedef float f32x4 __attribute__((ext_vector_type(4)));
typedef unsigned char u8;

#define HDIM 256
#define TST 128
#define OUTD 10
#define S2LE 2.8853900817779268f   // 2*log2(e)

static __device__ __forceinline__ f16x2 pkrtz(float a, float b) {
  auto r = __builtin_amdgcn_cvt_pkrtz(a, b);
  return *(f16x2*)&r;
}

// R12 verbatim (4 waves x 64 rows, double-pump, own-chunk Gram stats,
// zeros-C-fold, setprio RESTORED — its removal cost 18us in R14)
// + one-time anti-phase desync: odd blocks s_sleep ~1500cyc before the main
//   loop so the two co-resident blocks' MFMA/VALU sections interleave instead
//   of lockstepping on the same pipe.
__global__ __launch_bounds__(256, 2) void rnn_kernel(
    const float* __restrict__ x,
    const float* __restrict__ embed_w,
    const float* __restrict__ embed_b,
    const float* __restrict__ update_w,
    const float* __restrict__ update_b,
    const float* __restrict__ gamma,
    const float* __restrict__ beta,
    const float* __restrict__ out_w,
    const float* __restrict__ out_b,
    float* __restrict__ out)
{
  __shared__ __align__(16) f16   sFR[2][8][64][8];   // 16 KB; overlays: T0 (init), sOut (epi)
  __shared__ __align__(16) float sD1[10 * 260];      // 10.4 KB; epi overlay: sOW
  __shared__ __align__(16) float sBW[HDIM];
  __shared__ __align__(16) float sRSg[HDIM];
  __shared__ __align__(16) float sST[2][16][10][2];  // [group][col][slot 2w+cp][s1,s2]
  __shared__ float sOB[16];
  __shared__ u8    sXb[TST][32];

  const int tid = threadIdx.x;
  const int w  = tid >> 6;      // 0..3
  const int l  = tid & 63;
  const int q  = l >> 4;
  const int ml = l & 15;
  const int m3 = ml & 3;
  const int base = blockIdx.x * 32;
  const int nb = w * 64 + q * 4;
  const int diagw = (q == (ml >> 2));     // lane holds Gram diag for col ml

  float* T0 = (float*)&sFR[0][0][0][0];   // [256][10] init-only overlay

  // ---------- P-init 1 ----------
  {
    float ew = embed_w[tid], eb = embed_b[tid];
    #pragma unroll
    for (int xv = 0; xv < 10; xv++)
      T0[tid * 10 + xv] = tanhf((float)xv * ew + eb);
  }
  for (int idx = tid; idx < 32 * TST; idx += 256) {
    int col = idx >> 7, tt = idx & 127;
    sXb[tt][col] = (u8)(int)x[(size_t)(base + col) * TST + tt];
  }
  if (tid < 16) {
    float v = 0.f;
    if (tid < OUTD) {
      v = out_b[tid];
      const float* orow = out_w + tid * HDIM;
      for (int k = 0; k < HDIM; k += 4) {
        float4 wv = *(const float4*)(orow + k);
        float4 bv = *(const float4*)(beta + k);
        v = fmaf(wv.x, bv.x, fmaf(wv.y, bv.y, fmaf(wv.z, bv.z, fmaf(wv.w, bv.w, v))));
      }
    }
    sOB[tid] = v;
  }
  __syncthreads();

  // ---------- P-init 2: per-n tables (n = tid) ----------
  {
    const int n = tid;
    const float* wrow = update_w + n * HDIM;
    float ty[10];
    #pragma unroll
    for (int xv = 0; xv < 10; xv++) ty[xv] = 0.f;
    float bw = 0.f, rsg = 0.f;
    for (int k = 0; k < HDIM; k += 4) {
      float4 wv4 = *(const float4*)(wrow + k);
      float4 b4  = *(const float4*)(beta + k);
      float4 g4  = *(const float4*)(gamma + k);
      bw  = fmaf(wv4.x, b4.x, fmaf(wv4.y, b4.y, fmaf(wv4.z, b4.z, fmaf(wv4.w, b4.w, bw))));
      rsg = fmaf(wv4.x, S2LE * g4.x, fmaf(wv4.y, S2LE * g4.y,
            fmaf(wv4.z, S2LE * g4.z, fmaf(wv4.w, S2LE * g4.w, rsg))));
      #pragma unroll
      for (int kk = 0; kk < 4; kk++) {
        float wv = ((const float*)&wv4)[kk];
        const float* t0r = T0 + (k + kk) * 10;
        #pragma unroll
        for (int xv = 0; xv < 10; xv++) ty[xv] = fmaf(wv, t0r[xv], ty[xv]);
      }
    }
    float ubn = update_b[n];
    sBW[n]  = S2LE * bw;
    sRSg[n] = rsg;
    #pragma unroll
    for (int xv = 0; xv < 10; xv++)
      sD1[xv * 260 + n] = S2LE * (ty[xv] + ubn + bw);
  }
  __syncthreads();

  // ---------- W_g fragments (128 regs) ----------
  f16x8 wf[4][8];
  #pragma unroll
  for (int c = 0; c < 8; c++) {
    const int k0 = c * 32 + q * 4;
    float4 g0 = *(const float4*)(gamma + k0);
    float4 g1 = *(const float4*)(gamma + k0 + 16);
    #pragma unroll
    for (int nt = 0; nt < 4; nt++) {
      const float* wrow = update_w + (w * 64 + nt * 16 + ml) * HDIM;
      float4 a0 = *(const float4*)(wrow + k0);
      float4 a1 = *(const float4*)(wrow + k0 + 16);
      f16x8 f;
      f[0]=(f16)(S2LE*g0.x*a0.x); f[1]=(f16)(S2LE*g0.y*a0.y);
      f[2]=(f16)(S2LE*g0.z*a0.z); f[3]=(f16)(S2LE*g0.w*a0.w);
      f[4]=(f16)(S2LE*g1.x*a1.x); f[5]=(f16)(S2LE*g1.y*a1.y);
      f[6]=(f16)(S2LE*g1.z*a1.z); f[7]=(f16)(S2LE*g1.w*a1.w);
      wf[nt][c] = f;
    }
  }
  f32x4 rsgr[4];
  #pragma unroll
  for (int nt = 0; nt < 4; nt++)
    rsgr[nt] = *(const f32x4*)(sRSg + nb + nt * 16);

  f16x8 ones_;
  #pragma unroll
  for (int j = 0; j < 8; j++) ones_[j] = (f16)1.f;
  const f32x4 zeros_ = {0.f, 0.f, 0.f, 0.f};

  f32x4 acc0[4], acc1[4];

  // ---------- prologue t=0: tv(0) both groups -> frags (no stats) ----------
  {
    #pragma unroll
    for (int g = 0; g < 2; g++) {
      const int xv0 = (int)sXb[0][g * 16 + ml];
      const float* dp = sD1 + xv0 * 260;
      #pragma unroll
      for (int cp = 0; cp < 2; cp++) {
        union { f16x8 v8; f16x2 v2[4]; } pk;
        #pragma unroll
        for (int h = 0; h < 2; h++) {
          const int nt = 2 * cp + h;
          f32x4 dd = *(const f32x4*)(dp + nb + nt * 16);
          f32x4 bw = *(const f32x4*)(sBW + nb + nt * 16);
          float tq[4];
          #pragma unroll
          for (int r = 0; r < 4; r++) {
            float y = dd[r] - bw[r];
            float e = __builtin_amdgcn_exp2f(y);
            float tv = fmaf(-2.f, __builtin_amdgcn_rcpf(e + 1.f), 1.f);
            tq[r] = tv;
          }
          pk.v2[2 * h]     = pkrtz(tq[0], tq[1]);
          pk.v2[2 * h + 1] = pkrtz(tq[2], tq[3]);
        }
        *(f16x8*)&sFR[g][2 * w + cp][l][0] = pk.v8;
      }
    }
    __syncthreads();
  }

  // ---------- anti-phase desync: odd blocks offset ~1500 cycles ----------
  if (blockIdx.x & 1) {
    __builtin_amdgcn_s_sleep(23);   // 23*64 = 1472 cycles ~ half a phase
  }

#define MMG(FB, CC, CUR, NXT, ACC)                                             \
    { if ((CC) < 7) NXT = *(const f16x8*)((FB) + ((CC) + 1) * 512 + l * 8);    \
      ACC[0] = __builtin_amdgcn_mfma_f32_16x16x32_f16(wf[0][CC], CUR, ACC[0],0,0,0); \
      ACC[1] = __builtin_amdgcn_mfma_f32_16x16x32_f16(wf[1][CC], CUR, ACC[1],0,0,0); \
      ACC[2] = __builtin_amdgcn_mfma_f32_16x16x32_f16(wf[2][CC], CUR, ACC[2],0,0,0); \
      ACC[3] = __builtin_amdgcn_mfma_f32_16x16x32_f16(wf[3][CC], CUR, ACC[3],0,0,0); }

#define GSEL(AG, SEL)                                                          \
    { SEL = AG[0];                                                             \
      SEL = (m3 == 1) ? AG[1] : SEL;                                           \
      SEL = (m3 == 2) ? AG[2] : SEL;                                           \
      SEL = (m3 == 3) ? AG[3] : SEL; }

#define STATRD(G, S1, S2)                                                      \
    { const float* sp_ = &sST[G][ml][0][0];                                    \
      f32x4 a0_ = *(const f32x4*)(sp_);                                        \
      f32x4 a1_ = *(const f32x4*)(sp_ + 4);                                    \
      f32x4 a2_ = *(const f32x4*)(sp_ + 8);                                    \
      f32x4 a3_ = *(const f32x4*)(sp_ + 12);                                   \
      S1 = ((a0_[0] + a0_[2]) + (a1_[0] + a1_[2]))                             \
         + ((a2_[0] + a2_[2]) + (a3_[0] + a3_[2]));                            \
      S2 = ((a0_[1] + a0_[3]) + (a1_[1] + a1_[3]))                             \
         + ((a2_[1] + a2_[3]) + (a3_[1] + a3_[3])); }

// own-chunk stats for frags of group buffer FB (chunks 2w, 2w+1) -> sST[G]
#define STATOWN(FB, G)                                                         \
    { f16x8 ro0_ = *(const f16x8*)((FB) + (2 * w) * 512 + l * 8);              \
      f16x8 ro1_ = *(const f16x8*)((FB) + (2 * w + 1) * 512 + l * 8);          \
      f32x4 aG0_ = __builtin_amdgcn_mfma_f32_16x16x32_f16(ro0_, ro0_, zeros_,0,0,0); \
      f32x4 aS0_ = __builtin_amdgcn_mfma_f32_16x16x32_f16(ones_, ro0_, zeros_,0,0,0); \
      f32x4 aG1_ = __builtin_amdgcn_mfma_f32_16x16x32_f16(ro1_, ro1_, zeros_,0,0,0); \
      f32x4 aS1_ = __builtin_amdgcn_mfma_f32_16x16x32_f16(ones_, ro1_, zeros_,0,0,0); \
      float sel0_, sel1_;                                                      \
      GSEL(aG0_, sel0_)                                                        \
      GSEL(aG1_, sel1_)                                                        \
      if (diagw)                                                               \
        *(f32x4*)&sST[G][ml][2 * w][0] =                                       \
            (f32x4){aS0_[0], sel0_, aS1_[0], sel1_};                           \
    }

#define SLICE(S, ACCE)                                                         \
    { _Pragma("unroll") for (int r_ = 0; r_ < 4; r_++) {                       \
        float y_ = fmaf(rs_, ACCE[S][r_], fmaf(-rm_, rsgr[S][r_], dd_[S][r_]));\
        float e_ = __builtin_amdgcn_exp2f(y_);                                 \
        tv_[S][r_] = fmaf(-2.f, __builtin_amdgcn_rcpf(e_ + 1.f), 1.f); } }

#define PACK(GE, CP)                                                           \
    { union { f16x8 v8; f16x2 v2[4]; } k_;                                     \
      k_.v2[0] = pkrtz(tv_[2*(CP)][0],   tv_[2*(CP)][1]);                      \
      k_.v2[1] = pkrtz(tv_[2*(CP)][2],   tv_[2*(CP)][3]);                      \
      k_.v2[2] = pkrtz(tv_[2*(CP)+1][0], tv_[2*(CP)+1][1]);                    \
      k_.v2[3] = pkrtz(tv_[2*(CP)+1][2], tv_[2*(CP)+1][3]);                    \
      *(f16x8*)&sFR[GE][2 * w + (CP)][l][0] = k_.v8; }

// PHASE: MFMA group GM (frags sFR[GM] -> ACCM; own-chunk Gram -> sST[GM]) ||
// elementwise group GE at step TE (consumes ACCE + sST[GE]; packs tv -> sFR[GE]).
#define PHASE(TE, GM, GE, XOFF, ACCM, ACCE)                                    \
  {                                                                            \
    float s1_, s2_;                                                            \
    STATRD(GE, s1_, s2_)                                                       \
    const int xv_ = (int)sXb[TE][XOFF + ml];                                   \
    const float* dp_ = sD1 + xv_ * 260 + nb;                                   \
    f32x4 dd_[4];                                                              \
    _Pragma("unroll") for (int n_ = 0; n_ < 4; n_++)                           \
      dd_[n_] = *(const f32x4*)(dp_ + n_ * 16);                                \
    const f16* fbm_ = &sFR[GM][0][0][0];                                       \
    f16x8 rA_ = *(const f16x8*)(fbm_ + l * 8);                                 \
    f16x8 rB_;                                                                 \
    f32x4 tv_[4];                                                              \
    __builtin_amdgcn_s_setprio(1);                                             \
    rB_ = *(const f16x8*)(fbm_ + 512 + l * 8);                                 \
    ACCM[0] = __builtin_amdgcn_mfma_f32_16x16x32_f16(wf[0][0], rA_, zeros_,0,0,0); \
    ACCM[1] = __builtin_amdgcn_mfma_f32_16x16x32_f16(wf[1][0], rA_, zeros_,0,0,0); \
    ACCM[2] = __builtin_amdgcn_mfma_f32_16x16x32_f16(wf[2][0], rA_, zeros_,0,0,0); \
    ACCM[3] = __builtin_amdgcn_mfma_f32_16x16x32_f16(wf[3][0], rA_, zeros_,0,0,0); \
    MMG(fbm_, 1, rB_, rA_, ACCM)                                               \
    float mu_ = s1_ * (1.f / 256.f);                                           \
    float rs_ = __frsqrt_rn(fmaf(s2_, 1.f / 256.f, -mu_ * mu_) + 1e-5f);       \
    float rm_ = rs_ * mu_;                                                     \
    SLICE(0, ACCE)                                                             \
    MMG(fbm_, 2, rA_, rB_, ACCM)                                               \
    MMG(fbm_, 3, rB_, rA_, ACCM)                                               \
    SLICE(1, ACCE)                                                             \
    PACK(GE, 0)                                                                \
    MMG(fbm_, 4, rA_, rB_, ACCM)                                               \
    MMG(fbm_, 5, rB_, rA_, ACCM)                                               \
    SLICE(2, ACCE)                                                             \
    MMG(fbm_, 6, rA_, rB_, ACCM)                                               \
    MMG(fbm_, 7, rB_, rA_, ACCM)                                               \
    SLICE(3, ACCE)                                                             \
    PACK(GE, 1)                                                                \
    STATOWN(fbm_, GM)                                                          \
    __builtin_amdgcn_s_setprio(0);                                             \
    __syncthreads();                                                           \
  }

  // ---------- P0(1): MFMA g0 + own-chunk stats(g0,0) ----------
  {
    const f16* fbm_ = &sFR[0][0][0][0];
    f16x8 rA_ = *(const f16x8*)(fbm_ + l * 8);
    f16x8 rB_;
    rB_ = *(const f16x8*)(fbm_ + 512 + l * 8);
    acc0[0] = __builtin_amdgcn_mfma_f32_16x16x32_f16(wf[0][0], rA_, zeros_,0,0,0);
    acc0[1] = __builtin_amdgcn_mfma_f32_16x16x32_f16(wf[1][0], rA_, zeros_,0,0,0);
    acc0[2] = __builtin_amdgcn_mfma_f32_16x16x32_f16(wf[2][0], rA_, zeros_,0,0,0);
    acc0[3] = __builtin_amdgcn_mfma_f32_16x16x32_f16(wf[3][0], rA_, zeros_,0,0,0);
    MMG(fbm_, 1, rB_, rA_, acc0)
    MMG(fbm_, 2, rA_, rB_, acc0)
    MMG(fbm_, 3, rB_, rA_, acc0)
    MMG(fbm_, 4, rA_, rB_, acc0)
    MMG(fbm_, 5, rB_, rA_, acc0)
    MMG(fbm_, 6, rA_, rB_, acc0)
    MMG(fbm_, 7, rB_, rA_, acc0)
    STATOWN(fbm_, 0)
    __syncthreads();
  }

  // ---------- main loop: 2 phases per step, single-buffered sST ----------
  #pragma unroll 1
  for (int t = 1; t <= 127; t++) {
    PHASE(t, 1, 0, 0,  acc1, acc0)
    PHASE(t, 0, 1, 16, acc0, acc1)
  }
  // post: sFR[0]=tv(g0,127), sFR[1]=tv(g1,127);
  //       sST[0]=stats(g0,127); sST[1]=stats(g1,126) stale -> recompute.

  // ---------- epilogue ----------
  {
    const f16* fb1 = &sFR[1][0][0][0];
    STATOWN(fb1, 1)
    f16x8 fin0[2], fin1[2];
    #pragma unroll
    for (int cp = 0; cp < 2; cp++) {
      fin0[cp] = *(const f16x8*)&sFR[0][2 * w + cp][l][0];
      fin1[cp] = *(const f16x8*)&sFR[1][2 * w + cp][l][0];
    }
    __syncthreads();

    float rsF[2], nmF[2];
    {
      float s1, s2;
      STATRD(0, s1, s2)
      float mu = s1 * (1.f / 256.f);
      float ve = fmaf(s2, 1.f / 256.f, -mu * mu) + 1e-5f;
      rsF[0] = __frsqrt_rn(ve); nmF[0] = -rsF[0] * mu;
      STATRD(1, s1, s2)
      mu = s1 * (1.f / 256.f);
      ve = fmaf(s2, 1.f / 256.f, -mu * mu) + 1e-5f;
      rsF[1] = __frsqrt_rn(ve); nmF[1] = -rsF[1] * mu;
    }

    f16* sOW = (f16*)sD1;
    for (int idx = tid; idx < 512; idx += 256) {
      int c = idx >> 6, l2 = idx & 63, q2 = l2 >> 4, o = l2 & 15;
      int k0 = c * 32 + q2 * 4;
      f16x8 f;
      #pragma unroll
      for (int j = 0; j < 8; j++) f[j] = (f16)0.f;
      if (o < OUTD) {
        const float* orow = out_w + o * HDIM;
        float4 a0 = *(const float4*)(orow + k0);
        float4 a1 = *(const float4*)(orow + k0 + 16);
        float4 g0 = *(const float4*)(gamma + k0);
        float4 g1 = *(const float4*)(gamma + k0 + 16);
        f[0]=(f16)(g0.x*a0.x); f[1]=(f16)(g0.y*a0.y); f[2]=(f16)(g0.z*a0.z); f[3]=(f16)(g0.w*a0.w);
        f[4]=(f16)(g1.x*a1.x); f[5]=(f16)(g1.y*a1.y); f[6]=(f16)(g1.z*a1.z); f[7]=(f16)(g1.w*a1.w);
      }
      *(f16x8*)(sOW + idx * 8) = f;
    }
    __syncthreads();

    float* sOut = (float*)&sFR[0][0][0][0];  // [2][4][16][16] f32 = 8 KB overlay
    #pragma unroll
    for (int g = 0; g < 2; g++) {
      f32x4 aO = zeros_;
      #pragma unroll
      for (int cp = 0; cp < 2; cp++) {
        f16x8 fr = (g == 0) ? fin0[cp] : fin1[cp];
        f16x8 af;
        #pragma unroll
        for (int j = 0; j < 8; j++)
          af[j] = (f16)fmaf(rsF[g], (float)fr[j], nmF[g]);
        f16x8 of = *(const f16x8*)(sOW + ((size_t)(2 * w + cp) * 64 + l) * 8);
        aO = __builtin_amdgcn_mfma_f32_16x16x32_f16(of, af, aO, 0, 0, 0);
      }
      #pragma unroll
      for (int r = 0; r < 4; r++)
        sOut[((g * 4 + w) * 16 + ml) * 16 + q * 4 + r] = aO[r];
    }
    __syncthreads();
    for (int idx = tid; idx < 32 * OUTD; idx += 256) {
      int m = idx / OUTD, o = idx - m * OUTD;
      int g = m >> 4, mm = m & 15;
      float s = 0.f;
      #pragma unroll
      for (int ww = 0; ww < 4; ww++) s += sOut[((g * 4 + ww) * 16 + mm) * 16 + o];
      out[(size_t)(base + m) * OUTD + o] = s + sOB[o];
    }
  }
}

extern "C" void kernel_launch(void* const* d_in, const int* in_sizes, int n_in,
                              void* d_out, int out_size, void* d_ws, size_t ws_size,
                              hipStream_t stream) {
  const float* x   = (const float*)d_in[0];
  const float* ew  = (const float*)d_in[1];
  const float* eb  = (const float*)d_in[2];
  const float* uw  = (const float*)d_in[3];
  const float* ub  = (const float*)d_in[4];
  const float* g   = (const float*)d_in[5];
  const float* be  = (const float*)d_in[6];
  const float* ow  = (const float*)d_in[7];
  const float* ob  = (const float*)d_in[8];
  float* out = (float*)d_out;

  const int B = in_sizes[0] / TST;      // 16384
  const int grid = B / 32;              // 512 blocks = 2/CU, one round
  hipLaunchKernelGGL(rnn_kernel, dim3(grid), dim3(256), 0, stream,
                     x, ew, eb, uw, ub, g, be, ow, ob, out);
}

// Round 16
// 317.700 us; speedup vs baseline: 1.2019x; 1.0589x over previous
//
#include <hip/hip_runtime.h>
#include <hip/hip_fp16.h>
#include <math.h>

typedef _Float16 f16;
typedef _Float16 f16x2 __attribute__((ext_vector_type(2)));
typedef _Float16 f16x8 __attribute__((ext_vector_type(8)));
typedef float f32x4 __attribute__((ext_vector_type(4)));
typedef unsigned char u8;

#define HDIM 256
#define TST 128
#define OUTD 10
#define S2LE 2.8853900817779268f   // 2*log2(e)

static __device__ __forceinline__ f16x2 pkrtz(float a, float b) {
  auto r = __builtin_amdgcn_cvt_pkrtz(a, b);
  return *(f16x2*)&r;
}

// R12 verbatim — verified best (318 us, VGPR 124, FETCH 5.3 MB, no spill).
// 4 waves x 64 hidden rows, 32 batch cols in 2 groups, double-pump,
// own-chunk MFMA-Gram stats via sST slots, zeros-C-fold, setprio kept
// (removal cost 18 us in R14; additions in R13/R15 spilled: FETCH 15-31 MB).
__global__ __launch_bounds__(256, 2) void rnn_kernel(
    const float* __restrict__ x,
    const float* __restrict__ embed_w,
    const float* __restrict__ embed_b,
    const float* __restrict__ update_w,
    const float* __restrict__ update_b,
    const float* __restrict__ gamma,
    const float* __restrict__ beta,
    const float* __restrict__ out_w,
    const float* __restrict__ out_b,
    float* __restrict__ out)
{
  __shared__ __align__(16) f16   sFR[2][8][64][8];   // 16 KB; overlays: T0 (init), sOut (epi)
  __shared__ __align__(16) float sD1[10 * 260];      // 10.4 KB; epi overlay: sOW
  __shared__ __align__(16) float sBW[HDIM];
  __shared__ __align__(16) float sRSg[HDIM];
  __shared__ __align__(16) float sST[2][16][10][2];  // [group][col][slot 2w+cp][s1,s2]
  __shared__ float sOB[16];
  __shared__ u8    sXb[TST][32];

  const int tid = threadIdx.x;
  const int w  = tid >> 6;      // 0..3
  const int l  = tid & 63;
  const int q  = l >> 4;
  const int ml = l & 15;
  const int m3 = ml & 3;
  const int base = blockIdx.x * 32;
  const int nb = w * 64 + q * 4;
  const int diagw = (q == (ml >> 2));     // lane holds Gram diag for col ml

  float* T0 = (float*)&sFR[0][0][0][0];   // [256][10] init-only overlay

  // ---------- P-init 1 ----------
  {
    float ew = embed_w[tid], eb = embed_b[tid];
    #pragma unroll
    for (int xv = 0; xv < 10; xv++)
      T0[tid * 10 + xv] = tanhf((float)xv * ew + eb);
  }
  for (int idx = tid; idx < 32 * TST; idx += 256) {
    int col = idx >> 7, tt = idx & 127;
    sXb[tt][col] = (u8)(int)x[(size_t)(base + col) * TST + tt];
  }
  if (tid < 16) {
    float v = 0.f;
    if (tid < OUTD) {
      v = out_b[tid];
      const float* orow = out_w + tid * HDIM;
      for (int k = 0; k < HDIM; k += 4) {
        float4 wv = *(const float4*)(orow + k);
        float4 bv = *(const float4*)(beta + k);
        v = fmaf(wv.x, bv.x, fmaf(wv.y, bv.y, fmaf(wv.z, bv.z, fmaf(wv.w, bv.w, v))));
      }
    }
    sOB[tid] = v;
  }
  __syncthreads();

  // ---------- P-init 2: per-n tables (n = tid) ----------
  {
    const int n = tid;
    const float* wrow = update_w + n * HDIM;
    float ty[10];
    #pragma unroll
    for (int xv = 0; xv < 10; xv++) ty[xv] = 0.f;
    float bw = 0.f, rsg = 0.f;
    for (int k = 0; k < HDIM; k += 4) {
      float4 wv4 = *(const float4*)(wrow + k);
      float4 b4  = *(const float4*)(beta + k);
      float4 g4  = *(const float4*)(gamma + k);
      bw  = fmaf(wv4.x, b4.x, fmaf(wv4.y, b4.y, fmaf(wv4.z, b4.z, fmaf(wv4.w, b4.w, bw))));
      rsg = fmaf(wv4.x, S2LE * g4.x, fmaf(wv4.y, S2LE * g4.y,
            fmaf(wv4.z, S2LE * g4.z, fmaf(wv4.w, S2LE * g4.w, rsg))));
      #pragma unroll
      for (int kk = 0; kk < 4; kk++) {
        float wv = ((const float*)&wv4)[kk];
        const float* t0r = T0 + (k + kk) * 10;
        #pragma unroll
        for (int xv = 0; xv < 10; xv++) ty[xv] = fmaf(wv, t0r[xv], ty[xv]);
      }
    }
    float ubn = update_b[n];
    sBW[n]  = S2LE * bw;
    sRSg[n] = rsg;
    #pragma unroll
    for (int xv = 0; xv < 10; xv++)
      sD1[xv * 260 + n] = S2LE * (ty[xv] + ubn + bw);
  }
  __syncthreads();

  // ---------- W_g fragments (128 regs) ----------
  f16x8 wf[4][8];
  #pragma unroll
  for (int c = 0; c < 8; c++) {
    const int k0 = c * 32 + q * 4;
    float4 g0 = *(const float4*)(gamma + k0);
    float4 g1 = *(const float4*)(gamma + k0 + 16);
    #pragma unroll
    for (int nt = 0; nt < 4; nt++) {
      const float* wrow = update_w + (w * 64 + nt * 16 + ml) * HDIM;
      float4 a0 = *(const float4*)(wrow + k0);
      float4 a1 = *(const float4*)(wrow + k0 + 16);
      f16x8 f;
      f[0]=(f16)(S2LE*g0.x*a0.x); f[1]=(f16)(S2LE*g0.y*a0.y);
      f[2]=(f16)(S2LE*g0.z*a0.z); f[3]=(f16)(S2LE*g0.w*a0.w);
      f[4]=(f16)(S2LE*g1.x*a1.x); f[5]=(f16)(S2LE*g1.y*a1.y);
      f[6]=(f16)(S2LE*g1.z*a1.z); f[7]=(f16)(S2LE*g1.w*a1.w);
      wf[nt][c] = f;
    }
  }
  f32x4 rsgr[4];
  #pragma unroll
  for (int nt = 0; nt < 4; nt++)
    rsgr[nt] = *(const f32x4*)(sRSg + nb + nt * 16);

  f16x8 ones_;
  #pragma unroll
  for (int j = 0; j < 8; j++) ones_[j] = (f16)1.f;
  const f32x4 zeros_ = {0.f, 0.f, 0.f, 0.f};

  f32x4 acc0[4], acc1[4];

  // ---------- prologue t=0: tv(0) both groups -> frags (no stats) ----------
  {
    #pragma unroll
    for (int g = 0; g < 2; g++) {
      const int xv0 = (int)sXb[0][g * 16 + ml];
      const float* dp = sD1 + xv0 * 260;
      #pragma unroll
      for (int cp = 0; cp < 2; cp++) {
        union { f16x8 v8; f16x2 v2[4]; } pk;
        #pragma unroll
        for (int h = 0; h < 2; h++) {
          const int nt = 2 * cp + h;
          f32x4 dd = *(const f32x4*)(dp + nb + nt * 16);
          f32x4 bw = *(const f32x4*)(sBW + nb + nt * 16);
          float tq[4];
          #pragma unroll
          for (int r = 0; r < 4; r++) {
            float y = dd[r] - bw[r];
            float e = __builtin_amdgcn_exp2f(y);
            float tv = fmaf(-2.f, __builtin_amdgcn_rcpf(e + 1.f), 1.f);
            tq[r] = tv;
          }
          pk.v2[2 * h]     = pkrtz(tq[0], tq[1]);
          pk.v2[2 * h + 1] = pkrtz(tq[2], tq[3]);
        }
        *(f16x8*)&sFR[g][2 * w + cp][l][0] = pk.v8;
      }
    }
    __syncthreads();
  }

#define MMG(FB, CC, CUR, NXT, ACC)                                             \
    { if ((CC) < 7) NXT = *(const f16x8*)((FB) + ((CC) + 1) * 512 + l * 8);    \
      ACC[0] = __builtin_amdgcn_mfma_f32_16x16x32_f16(wf[0][CC], CUR, ACC[0],0,0,0); \
      ACC[1] = __builtin_amdgcn_mfma_f32_16x16x32_f16(wf[1][CC], CUR, ACC[1],0,0,0); \
      ACC[2] = __builtin_amdgcn_mfma_f32_16x16x32_f16(wf[2][CC], CUR, ACC[2],0,0,0); \
      ACC[3] = __builtin_amdgcn_mfma_f32_16x16x32_f16(wf[3][CC], CUR, ACC[3],0,0,0); }

#define GSEL(AG, SEL)                                                          \
    { SEL = AG[0];                                                             \
      SEL = (m3 == 1) ? AG[1] : SEL;                                           \
      SEL = (m3 == 2) ? AG[2] : SEL;                                           \
      SEL = (m3 == 3) ? AG[3] : SEL; }

#define STATRD(G, S1, S2)                                                      \
    { const float* sp_ = &sST[G][ml][0][0];                                    \
      f32x4 a0_ = *(const f32x4*)(sp_);                                        \
      f32x4 a1_ = *(const f32x4*)(sp_ + 4);                                    \
      f32x4 a2_ = *(const f32x4*)(sp_ + 8);                                    \
      f32x4 a3_ = *(const f32x4*)(sp_ + 12);                                   \
      S1 = ((a0_[0] + a0_[2]) + (a1_[0] + a1_[2]))                             \
         + ((a2_[0] + a2_[2]) + (a3_[0] + a3_[2]));                            \
      S2 = ((a0_[1] + a0_[3]) + (a1_[1] + a1_[3]))                             \
         + ((a2_[1] + a2_[3]) + (a3_[1] + a3_[3])); }

// own-chunk stats for frags of group buffer FB (chunks 2w, 2w+1) -> sST[G]
#define STATOWN(FB, G)                                                         \
    { f16x8 ro0_ = *(const f16x8*)((FB) + (2 * w) * 512 + l * 8);              \
      f16x8 ro1_ = *(const f16x8*)((FB) + (2 * w + 1) * 512 + l * 8);          \
      f32x4 aG0_ = __builtin_amdgcn_mfma_f32_16x16x32_f16(ro0_, ro0_, zeros_,0,0,0); \
      f32x4 aS0_ = __builtin_amdgcn_mfma_f32_16x16x32_f16(ones_, ro0_, zeros_,0,0,0); \
      f32x4 aG1_ = __builtin_amdgcn_mfma_f32_16x16x32_f16(ro1_, ro1_, zeros_,0,0,0); \
      f32x4 aS1_ = __builtin_amdgcn_mfma_f32_16x16x32_f16(ones_, ro1_, zeros_,0,0,0); \
      float sel0_, sel1_;                                                      \
      GSEL(aG0_, sel0_)                                                        \
      GSEL(aG1_, sel1_)                                                        \
      if (diagw)                                                               \
        *(f32x4*)&sST[G][ml][2 * w][0] =                                       \
            (f32x4){aS0_[0], sel0_, aS1_[0], sel1_};                           \
    }

#define SLICE(S, ACCE)                                                         \
    { _Pragma("unroll") for (int r_ = 0; r_ < 4; r_++) {                       \
        float y_ = fmaf(rs_, ACCE[S][r_], fmaf(-rm_, rsgr[S][r_], dd_[S][r_]));\
        float e_ = __builtin_amdgcn_exp2f(y_);                                 \
        tv_[S][r_] = fmaf(-2.f, __builtin_amdgcn_rcpf(e_ + 1.f), 1.f); } }

#define PACK(GE, CP)                                                           \
    { union { f16x8 v8; f16x2 v2[4]; } k_;                                     \
      k_.v2[0] = pkrtz(tv_[2*(CP)][0],   tv_[2*(CP)][1]);                      \
      k_.v2[1] = pkrtz(tv_[2*(CP)][2],   tv_[2*(CP)][3]);                      \
      k_.v2[2] = pkrtz(tv_[2*(CP)+1][0], tv_[2*(CP)+1][1]);                    \
      k_.v2[3] = pkrtz(tv_[2*(CP)+1][2], tv_[2*(CP)+1][3]);                    \
      *(f16x8*)&sFR[GE][2 * w + (CP)][l][0] = k_.v8; }

// PHASE: MFMA group GM (frags sFR[GM] -> ACCM; own-chunk Gram -> sST[GM]) ||
// elementwise group GE at step TE (consumes ACCE + sST[GE]; packs tv -> sFR[GE]).
#define PHASE(TE, GM, GE, XOFF, ACCM, ACCE)                                    \
  {                                                                            \
    float s1_, s2_;                                                            \
    STATRD(GE, s1_, s2_)                                                       \
    const int xv_ = (int)sXb[TE][XOFF + ml];                                   \
    const float* dp_ = sD1 + xv_ * 260 + nb;                                   \
    f32x4 dd_[4];                                                              \
    _Pragma("unroll") for (int n_ = 0; n_ < 4; n_++)                           \
      dd_[n_] = *(const f32x4*)(dp_ + n_ * 16);                                \
    const f16* fbm_ = &sFR[GM][0][0][0];                                       \
    f16x8 rA_ = *(const f16x8*)(fbm_ + l * 8);                                 \
    f16x8 rB_;                                                                 \
    f32x4 tv_[4];                                                              \
    __builtin_amdgcn_s_setprio(1);                                             \
    rB_ = *(const f16x8*)(fbm_ + 512 + l * 8);                                 \
    ACCM[0] = __builtin_amdgcn_mfma_f32_16x16x32_f16(wf[0][0], rA_, zeros_,0,0,0); \
    ACCM[1] = __builtin_amdgcn_mfma_f32_16x16x32_f16(wf[1][0], rA_, zeros_,0,0,0); \
    ACCM[2] = __builtin_amdgcn_mfma_f32_16x16x32_f16(wf[2][0], rA_, zeros_,0,0,0); \
    ACCM[3] = __builtin_amdgcn_mfma_f32_16x16x32_f16(wf[3][0], rA_, zeros_,0,0,0); \
    MMG(fbm_, 1, rB_, rA_, ACCM)                                               \
    float mu_ = s1_ * (1.f / 256.f);                                           \
    float rs_ = __frsqrt_rn(fmaf(s2_, 1.f / 256.f, -mu_ * mu_) + 1e-5f);       \
    float rm_ = rs_ * mu_;                                                     \
    SLICE(0, ACCE)                                                             \
    MMG(fbm_, 2, rA_, rB_, ACCM)                                               \
    MMG(fbm_, 3, rB_, rA_, ACCM)                                               \
    SLICE(1, ACCE)                                                             \
    PACK(GE, 0)                                                                \
    MMG(fbm_, 4, rA_, rB_, ACCM)                                               \
    MMG(fbm_, 5, rB_, rA_, ACCM)                                               \
    SLICE(2, ACCE)                                                             \
    MMG(fbm_, 6, rA_, rB_, ACCM)                                               \
    MMG(fbm_, 7, rB_, rA_, ACCM)                                               \
    SLICE(3, ACCE)                                                             \
    PACK(GE, 1)                                                                \
    STATOWN(fbm_, GM)                                                          \
    __builtin_amdgcn_s_setprio(0);                                             \
    __syncthreads();                                                           \
  }

  // ---------- P0(1): MFMA g0 + own-chunk stats(g0,0) ----------
  {
    const f16* fbm_ = &sFR[0][0][0][0];
    f16x8 rA_ = *(const f16x8*)(fbm_ + l * 8);
    f16x8 rB_;
    rB_ = *(const f16x8*)(fbm_ + 512 + l * 8);
    acc0[0] = __builtin_amdgcn_mfma_f32_16x16x32_f16(wf[0][0], rA_, zeros_,0,0,0);
    acc0[1] = __builtin_amdgcn_mfma_f32_16x16x32_f16(wf[1][0], rA_, zeros_,0,0,0);
    acc0[2] = __builtin_amdgcn_mfma_f32_16x16x32_f16(wf[2][0], rA_, zeros_,0,0,0);
    acc0[3] = __builtin_amdgcn_mfma_f32_16x16x32_f16(wf[3][0], rA_, zeros_,0,0,0);
    MMG(fbm_, 1, rB_, rA_, acc0)
    MMG(fbm_, 2, rA_, rB_, acc0)
    MMG(fbm_, 3, rB_, rA_, acc0)
    MMG(fbm_, 4, rA_, rB_, acc0)
    MMG(fbm_, 5, rB_, rA_, acc0)
    MMG(fbm_, 6, rA_, rB_, acc0)
    MMG(fbm_, 7, rB_, rA_, acc0)
    STATOWN(fbm_, 0)
    __syncthreads();
  }

  // ---------- main loop: 2 phases per step, single-buffered sST ----------
  #pragma unroll 1
  for (int t = 1; t <= 127; t++) {
    PHASE(t, 1, 0, 0,  acc1, acc0)
    PHASE(t, 0, 1, 16, acc0, acc1)
  }
  // post: sFR[0]=tv(g0,127), sFR[1]=tv(g1,127);
  //       sST[0]=stats(g0,127); sST[1]=stats(g1,126) stale -> recompute.

  // ---------- epilogue ----------
  {
    const f16* fb1 = &sFR[1][0][0][0];
    STATOWN(fb1, 1)
    f16x8 fin0[2], fin1[2];
    #pragma unroll
    for (int cp = 0; cp < 2; cp++) {
      fin0[cp] = *(const f16x8*)&sFR[0][2 * w + cp][l][0];
      fin1[cp] = *(const f16x8*)&sFR[1][2 * w + cp][l][0];
    }
    __syncthreads();

    float rsF[2], nmF[2];
    {
      float s1, s2;
      STATRD(0, s1, s2)
      float mu = s1 * (1.f / 256.f);
      float ve = fmaf(s2, 1.f / 256.f, -mu * mu) + 1e-5f;
      rsF[0] = __frsqrt_rn(ve); nmF[0] = -rsF[0] * mu;
      STATRD(1, s1, s2)
      mu = s1 * (1.f / 256.f);
      ve = fmaf(s2, 1.f / 256.f, -mu * mu) + 1e-5f;
      rsF[1] = __frsqrt_rn(ve); nmF[1] = -rsF[1] * mu;
    }

    f16* sOW = (f16*)sD1;
    for (int idx = tid; idx < 512; idx += 256) {
      int c = idx >> 6, l2 = idx & 63, q2 = l2 >> 4, o = l2 & 15;
      int k0 = c * 32 + q2 * 4;
      f16x8 f;
      #pragma unroll
      for (int j = 0; j < 8; j++) f[j] = (f16)0.f;
      if (o < OUTD) {
        const float* orow = out_w + o * HDIM;
        float4 a0 = *(const float4*)(orow + k0);
        float4 a1 = *(const float4*)(orow + k0 + 16);
        float4 g0 = *(const float4*)(gamma + k0);
        float4 g1 = *(const float4*)(gamma + k0 + 16);
        f[0]=(f16)(g0.x*a0.x); f[1]=(f16)(g0.y*a0.y); f[2]=(f16)(g0.z*a0.z); f[3]=(f16)(g0.w*a0.w);
        f[4]=(f16)(g1.x*a1.x); f[5]=(f16)(g1.y*a1.y); f[6]=(f16)(g1.z*a1.z); f[7]=(f16)(g1.w*a1.w);
      }
      *(f16x8*)(sOW + idx * 8) = f;
    }
    __syncthreads();

    float* sOut = (float*)&sFR[0][0][0][0];  // [2][4][16][16] f32 = 8 KB overlay
    #pragma unroll
    for (int g = 0; g < 2; g++) {
      f32x4 aO = zeros_;
      #pragma unroll
      for (int cp = 0; cp < 2; cp++) {
        f16x8 fr = (g == 0) ? fin0[cp] : fin1[cp];
        f16x8 af;
        #pragma unroll
        for (int j = 0; j < 8; j++)
          af[j] = (f16)fmaf(rsF[g], (float)fr[j], nmF[g]);
        f16x8 of = *(const f16x8*)(sOW + ((size_t)(2 * w + cp) * 64 + l) * 8);
        aO = __builtin_amdgcn_mfma_f32_16x16x32_f16(of, af, aO, 0, 0, 0);
      }
      #pragma unroll
      for (int r = 0; r < 4; r++)
        sOut[((g * 4 + w) * 16 + ml) * 16 + q * 4 + r] = aO[r];
    }
    __syncthreads();
    for (int idx = tid; idx < 32 * OUTD; idx += 256) {
      int m = idx / OUTD, o = idx - m * OUTD;
      int g = m >> 4, mm = m & 15;
      float s = 0.f;
      #pragma unroll
      for (int ww = 0; ww < 4; ww++) s += sOut[((g * 4 + ww) * 16 + mm) * 16 + o];
      out[(size_t)(base + m) * OUTD + o] = s + sOB[o];
    }
  }
}

extern "C" void kernel_launch(void* const* d_in, const int* in_sizes, int n_in,
                              void* d_out, int out_size, void* d_ws, size_t ws_size,
                              hipStream_t stream) {
  const float* x   = (const float*)d_in[0];
  const float* ew  = (const float*)d_in[1];
  const float* eb  = (const float*)d_in[2];
  const float* uw  = (const float*)d_in[3];
  const float* ub  = (const float*)d_in[4];
  const float* g   = (const float*)d_in[5];
  const float* be  = (const float*)d_in[6];
  const float* ow  = (const float*)d_in[7];
  const float* ob  = (const float*)d_in[8];
  float* out = (float*)d_out;

  const int B = in_sizes[0] / TST;      // 16384
  const int grid = B / 32;              // 512 blocks = 2/CU, one round
  hipLaunchKernelGGL(rnn_kernel, dim3(grid), dim3(256), 0, stream,
                     x, ew, eb, uw, ub, g, be, ow, ob, out);
}